// Round 4
// baseline (129.392 us; speedup 1.0000x reference)
//
#include <hip/hip_runtime.h>

// LNCC loss, shape (4,1,128,128,128) f32.
// scales=[32,64] w=[0.4,0.6], steps=[16,32], dilation=2.
// Only even (d,h,w) coords sampled => 64^3 even-subsampled volume.
// ksz=32 -> window 32 stride 8 (5/dim); ksz=64 -> full-volume sum.
// 8^3 chunks of 8^3 even voxels; window = 4x4x4 chunks.
// Single fused dispatch: 256 blocks x 512 thr compute chunk stats (8 batched
// float4 loads/thread), last-arriving block (device-scope atomic + fences,
// G16 cross-XCD) finalizes and writes the scalar. Counter zeroed by a 4-B
// memsetAsync (capture-legal) since the harness poisons d_ws to 0xAA.

#define NSTAT 5  // 0:x 1:y 2:x2 3:y2 4:xy

__global__ __launch_bounds__(512) void lncc_fused(
    const float* __restrict__ x, const float* __restrict__ y,
    float* ws /* [4][512][5] */, unsigned* counter, float* out) {
  const int blk = blockIdx.x;          // b*64 + ci*8 + cj
  const int b  = blk >> 6;
  const int ci = (blk >> 3) & 7;
  const int cj = blk & 7;
  const int tid = threadIdx.x;
  const int w4 = tid & 31;             // float4 index along w
  const int r  = tid >> 5;             // 0..15: s = r&7 (even-h row), ih = r>>3
  const int s  = r & 7;
  const int ih = r >> 3;

  const size_t base = (size_t)b * (128 * 128 * 128)
      + (size_t)((16 * ci + 8 * ih) * (128 * 128))
      + (size_t)((16 * cj + 2 * s) * 128)
      + (size_t)(w4 * 4);

  // 8 independent loads issued as one batch (32 VGPRs of payload)
  float4 ax[4], ay[4];
#pragma unroll
  for (int i = 0; i < 4; ++i)
    ax[i] = *(const float4*)(x + base + (size_t)(i * 2 * 128 * 128));
#pragma unroll
  for (int i = 0; i < 4; ++i)
    ay[i] = *(const float4*)(y + base + (size_t)(i * 2 * 128 * 128));

  float v[NSTAT] = {0.f, 0.f, 0.f, 0.f, 0.f};
#pragma unroll
  for (int i = 0; i < 4; ++i) {
    const float xa = ax[i].x, xb = ax[i].z;   // even-w lanes: .x and .z
    const float ya = ay[i].x, yb = ay[i].z;
    v[0] += xa + xb;
    v[1] += ya + yb;
    v[2] += xa * xa + xb * xb;
    v[3] += ya * ya + yb * yb;
    v[4] += xa * ya + xb * yb;
  }

  // wave-level fold: w4 bits (1,2) within a chunk, r parity (lane bit 5)
#pragma unroll
  for (int k = 0; k < NSTAT; ++k) {
    v[k] += __shfl_xor(v[k], 1);
    v[k] += __shfl_xor(v[k], 2);
    v[k] += __shfl_xor(v[k], 32);
  }

  const int lane = tid & 63, wave = tid >> 6, ck = w4 >> 2;
  __shared__ float sd[8 * 8 * NSTAT];  // [wave][ck][k]
  if ((lane & 3) == 0 && lane < 32) {
#pragma unroll
    for (int k = 0; k < NSTAT; ++k) sd[(wave * 8 + ck) * NSTAT + k] = v[k];
  }
  __syncthreads();

  if (tid < 8 * NSTAT) {               // 40 finalizers: ck = t/5, k = t%5
    const int c2 = tid / NSTAT, k = tid % NSTAT;
    float acc = 0.f;
#pragma unroll
    for (int wv = 0; wv < 8; ++wv) acc += sd[(wv * 8 + c2) * NSTAT + k];
    ws[((b * 512) + ci * 64 + cj * 8 + c2) * NSTAT + k] = acc;
  }

  // ---- release ws writes device-wide, then arrive ----
  __threadfence();
  __syncthreads();
  __shared__ unsigned lastflag;
  if (tid == 0) lastflag = (atomicAdd(counter, 1u) == 255u) ? 1u : 0u;
  __syncthreads();
  if (!lastflag) return;
  __threadfence();                     // acquire: invalidate stale caches

  // ---- finalize (one block, 512 threads) ----
  __shared__ float s5[2048 * NSTAT];   // 40 KB
  for (int i = tid; i < 2048 * NSTAT / 4; i += 512)
    ((float4*)s5)[i] = ((const float4*)ws)[i];
  __syncthreads();

  // per-batch totals (ksz=64): wave bb sums its 512 chunks
  __shared__ float totl[4 * NSTAT];
  if (wave < 4) {
    float tot[NSTAT] = {0.f, 0.f, 0.f, 0.f, 0.f};
    for (int c = lane; c < 512; c += 64) {
      const int idx = (wave * 512 + c) * NSTAT;
#pragma unroll
      for (int k = 0; k < NSTAT; ++k) tot[k] += s5[idx + k];
    }
#pragma unroll
    for (int off = 32; off; off >>= 1)
#pragma unroll
      for (int k = 0; k < NSTAT; ++k) tot[k] += __shfl_down(tot[k], off);
    if (lane == 0)
#pragma unroll
      for (int k = 0; k < NSTAT; ++k) totl[wave * NSTAT + k] = tot[k];
  }
  __syncthreads();

  // ksz=32 windows: 500, one per thread, each sums 4x4x4 chunks
  float lsum = 0.f;
  if (tid < 500) {
    const int b2 = tid / 125, rem = tid % 125;
    const int od = rem / 25, oh = (rem / 5) % 5, ow = rem % 5;
    float a0 = 0.f, a1 = 0.f, a2 = 0.f, a3 = 0.f, a4 = 0.f;
    for (int i = od; i < od + 4; ++i)
      for (int j = oh; j < oh + 4; ++j)
        for (int k2 = ow; k2 < ow + 4; ++k2) {
          const int idx = ((b2 * 512) + i * 64 + j * 8 + k2) * NSTAT;
          a0 += s5[idx];     a1 += s5[idx + 1];
          a2 += s5[idx + 2]; a3 += s5[idx + 3];
          a4 += s5[idx + 4];
        }
    const float numel = 32768.f;       // 32^3
    const float cross = a4 - a0 * a1 / numel;
    const float xv    = a2 - a0 * a0 / numel;
    const float yv    = a3 - a1 * a1 / numel;
    lsum = cross * cross / (xv * yv + 1e-5f);
  }
#pragma unroll
  for (int off = 32; off; off >>= 1) lsum += __shfl_down(lsum, off);
  __shared__ float wred[8];
  if (lane == 0) wred[wave] = lsum;
  __syncthreads();

  if (tid == 0) {
    float sum32 = 0.f;
    for (int i = 0; i < 8; ++i) sum32 += wred[i];
    const float mean32 = sum32 / 500.f;
    float sum64 = 0.f;
    for (int bb = 0; bb < 4; ++bb) {
      const float X  = totl[bb * NSTAT + 0], Y  = totl[bb * NSTAT + 1];
      const float X2 = totl[bb * NSTAT + 2], Y2 = totl[bb * NSTAT + 3];
      const float XY = totl[bb * NSTAT + 4];
      const float numel = 262144.f;    // 64^3
      const float cross = XY - X * Y / numel;
      const float xv    = X2 - X * X / numel;
      const float yv    = Y2 - Y * Y / numel;
      sum64 += cross * cross / (xv * yv + 1e-5f);
    }
    const float mean64 = sum64 * 0.25f;
    out[0] = (1.f - mean32) * 0.4f + (1.f - mean64) * 0.6f;
  }
}

extern "C" void kernel_launch(void* const* d_in, const int* in_sizes, int n_in,
                              void* d_out, int out_size, void* d_ws, size_t ws_size,
                              hipStream_t stream) {
  const float* x = (const float*)d_in[0];
  const float* y = (const float*)d_in[1];
  float* ws = (float*)d_ws;                          // 40960 B
  unsigned* counter = (unsigned*)((char*)d_ws + 40960);
  hipMemsetAsync(counter, 0, sizeof(unsigned), stream);
  lncc_fused<<<256, 512, 0, stream>>>(x, y, ws, counter, (float*)d_out);
}

// Round 5
// 91.971 us; speedup vs baseline: 1.4069x; 1.4069x over previous
//
#include <hip/hip_runtime.h>

// LNCC loss, shape (4,1,128,128,128) f32.
// scales=[32,64] w=[0.4,0.6], steps=[16,32], dilation=2.
// Only even (d,h,w) coords sampled => 64^3 even-subsampled volume.
// ksz=32 -> window 32 stride 8 (5/dim); ksz=64 -> full-volume sum.
// 8^3 chunks of 8^3 even voxels; window = 4x4x4 chunks, separable:
//   stage A (in pass1): sum over ck  -> A[b][ci][cj][ow][k] (25/block) and
//                        row totals T[b][ci][cj][k] (5/block)
//   stage B (pass2):    sum over cj  -> S2[b][ci][oh][ow][k] (4000)
//   stage C (pass2):    sum over ci  -> 500 windows, lncc formula
// Two dispatches: kernel boundary = device-wide sync (R4 showed the fused
// fence+atomic arrival path costs ~45-50 us regardless of load structure).

#define NSTAT 5  // 0:x 1:y 2:x2 3:y2 4:xy

__global__ __launch_bounds__(512) void lncc_pass1(
    const float* __restrict__ x, const float* __restrict__ y,
    float* __restrict__ wsA /* [256][25] */,
    float* __restrict__ wsT /* [256][5] */) {
  const int blk = blockIdx.x;          // b*64 + ci*8 + cj
  const int b  = blk >> 6;
  const int ci = (blk >> 3) & 7;
  const int cj = blk & 7;
  const int tid = threadIdx.x;
  const int w4 = tid & 31;             // float4 index along w
  const int r  = tid >> 5;             // 0..15: s = r&7 (even-h row), ih = r>>3
  const int s  = r & 7;
  const int ih = r >> 3;

  const size_t base = (size_t)b * (128 * 128 * 128)
      + (size_t)((16 * ci + 8 * ih) * (128 * 128))
      + (size_t)((16 * cj + 2 * s) * 128)
      + (size_t)(w4 * 4);

  // 8 independent loads issued as one batch (32 VGPRs of payload)
  float4 ax[4], ay[4];
#pragma unroll
  for (int i = 0; i < 4; ++i)
    ax[i] = *(const float4*)(x + base + (size_t)(i * 2 * 128 * 128));
#pragma unroll
  for (int i = 0; i < 4; ++i)
    ay[i] = *(const float4*)(y + base + (size_t)(i * 2 * 128 * 128));

  float v[NSTAT] = {0.f, 0.f, 0.f, 0.f, 0.f};
#pragma unroll
  for (int i = 0; i < 4; ++i) {
    const float xa = ax[i].x, xb = ax[i].z;   // even-w lanes: .x and .z
    const float ya = ay[i].x, yb = ay[i].z;
    v[0] += xa + xb;
    v[1] += ya + yb;
    v[2] += xa * xa + xb * xb;
    v[3] += ya * ya + yb * yb;
    v[4] += xa * ya + xb * yb;
  }

  // wave-level fold: w4 bits (1,2) within a chunk, s parity (lane bit 5)
#pragma unroll
  for (int k = 0; k < NSTAT; ++k) {
    v[k] += __shfl_xor(v[k], 1);
    v[k] += __shfl_xor(v[k], 2);
    v[k] += __shfl_xor(v[k], 32);
  }

  const int lane = tid & 63, wave = tid >> 6, ck = w4 >> 2;
  __shared__ float sd[8 * 8 * NSTAT];  // [wave][ck][k]
  __shared__ float c8[8][NSTAT];       // full chunk sums
  if ((lane & 3) == 0 && lane < 32) {
#pragma unroll
    for (int k = 0; k < NSTAT; ++k) sd[(wave * 8 + ck) * NSTAT + k] = v[k];
  }
  __syncthreads();

  if (tid < 8 * NSTAT) {               // 40 threads: c2 = t/5, k = t%5
    const int c2 = tid / NSTAT, k = tid % NSTAT;
    float acc = 0.f;
#pragma unroll
    for (int wv = 0; wv < 8; ++wv) acc += sd[(wv * 8 + c2) * NSTAT + k];
    c8[c2][k] = acc;
  }
  __syncthreads();

  if (tid < 25) {                      // stage A: ow = t/5, k = t%5
    const int ow = tid / 5, k = tid % 5;
    wsA[blk * 25 + tid] =
        c8[ow][k] + c8[ow + 1][k] + c8[ow + 2][k] + c8[ow + 3][k];
  } else if (tid < 30) {               // row totals
    const int k = tid - 25;
    float t = 0.f;
#pragma unroll
    for (int c = 0; c < 8; ++c) t += c8[c][k];
    wsT[blk * 5 + k] = t;
  }
}

__global__ __launch_bounds__(512) void lncc_pass2(
    const float* __restrict__ wsA, const float* __restrict__ wsT,
    float* __restrict__ out) {
  const int tid = threadIdx.x;
  const int wave = tid >> 6, lane = tid & 63;
  __shared__ float lA[6400];   // [b][ci][cj][ow][k], block stride 25
  __shared__ float lT[1280];   // [b][ci][cj][k],     block stride 5
  __shared__ float s2[4000];   // [b][ci][oh][ow][k]
  __shared__ float totl[4 * NSTAT];
  __shared__ float wred[8];

  for (int i = tid; i < 1600; i += 512)
    ((float4*)lA)[i] = ((const float4*)wsA)[i];
  for (int i = tid; i < 320; i += 512)
    ((float4*)lT)[i] = ((const float4*)wsT)[i];
  __syncthreads();

  // ---- stage B: sum over cj (stride 25 per cj in lA) ----
  for (int e = tid; e < 4000; e += 512) {
    const int k = e % 5, r1 = e / 5;
    const int ow = r1 % 5, r2 = r1 / 5;
    const int oh = r2 % 5, bc = r2 / 5;     // bc = b*8+ci
    const int bs = (bc * 8 + oh) * 25 + ow * 5 + k;
    s2[e] = lA[bs] + lA[bs + 25] + lA[bs + 50] + lA[bs + 75];
  }

  // ---- batch totals (ksz=64): wave bb, lane = (ci,cj) ----
  if (wave < 4) {
    float t[NSTAT];
#pragma unroll
    for (int k = 0; k < NSTAT; ++k) t[k] = lT[(wave * 64 + lane) * 5 + k];
#pragma unroll
    for (int off = 32; off; off >>= 1)
#pragma unroll
      for (int k = 0; k < NSTAT; ++k) t[k] += __shfl_down(t[k], off);
    if (lane == 0)
#pragma unroll
      for (int k = 0; k < NSTAT; ++k) totl[wave * NSTAT + k] = t[k];
  }
  __syncthreads();

  // ---- stage C: 500 windows, sum over ci (stride 125 in s2) ----
  float lsum = 0.f;
  if (tid < 500) {
    const int b2 = tid / 125, rem = tid % 125;
    const int od = rem / 25, oh = (rem / 5) % 5, ow = rem % 5;
    const int bs = (((b2 * 8 + od) * 5 + oh) * 5 + ow) * 5;
    float a[NSTAT];
#pragma unroll
    for (int k = 0; k < NSTAT; ++k)
      a[k] = s2[bs + k] + s2[bs + 125 + k] + s2[bs + 250 + k] + s2[bs + 375 + k];
    const float numel = 32768.f;       // 32^3
    const float cross = a[4] - a[0] * a[1] / numel;
    const float xv    = a[2] - a[0] * a[0] / numel;
    const float yv    = a[3] - a[1] * a[1] / numel;
    lsum = cross * cross / (xv * yv + 1e-5f);
  }
#pragma unroll
  for (int off = 32; off; off >>= 1) lsum += __shfl_down(lsum, off);
  if (lane == 0) wred[wave] = lsum;
  __syncthreads();

  if (tid == 0) {
    float sum32 = 0.f;
    for (int i = 0; i < 8; ++i) sum32 += wred[i];
    const float mean32 = sum32 / 500.f;
    float sum64 = 0.f;
    for (int bb = 0; bb < 4; ++bb) {
      const float X  = totl[bb * NSTAT + 0], Y  = totl[bb * NSTAT + 1];
      const float X2 = totl[bb * NSTAT + 2], Y2 = totl[bb * NSTAT + 3];
      const float XY = totl[bb * NSTAT + 4];
      const float numel = 262144.f;    // 64^3
      const float cross = XY - X * Y / numel;
      const float xv    = X2 - X * X / numel;
      const float yv    = Y2 - Y * Y / numel;
      sum64 += cross * cross / (xv * yv + 1e-5f);
    }
    const float mean64 = sum64 * 0.25f;
    out[0] = (1.f - mean32) * 0.4f + (1.f - mean64) * 0.6f;
  }
}

extern "C" void kernel_launch(void* const* d_in, const int* in_sizes, int n_in,
                              void* d_out, int out_size, void* d_ws, size_t ws_size,
                              hipStream_t stream) {
  const float* x = (const float*)d_in[0];
  const float* y = (const float*)d_in[1];
  float* wsA = (float*)d_ws;                         // 6400 floats
  float* wsT = (float*)((char*)d_ws + 6400 * 4);     // 1280 floats
  lncc_pass1<<<256, 512, 0, stream>>>(x, y, wsA, wsT);
  lncc_pass2<<<1, 512, 0, stream>>>(wsA, wsT, (float*)d_out);
}